// Round 7
// baseline (598.984 us; speedup 1.0000x reference)
//
#include <hip/hip_runtime.h>

#define D 32
#define NT 128
#define LOG2E 1.4426950408889634f

__device__ __forceinline__ void decode_pair(const void* comb, int B, int C,
                                            int pair, int flip, int& a, int& b) {
    const long long* c64 = (const long long*)comb;
    const int* c32 = (const int*)comb;
    bool is64 = true;
    for (int q = 0; q < C; ++q) {
        long long v = c64[q];
        if (v < 0 || v >= (long long)B) { is64 = false; break; }
    }
    if (is64) { a = (int)c64[2 * pair]; b = (int)c64[2 * pair + 1]; }
    else      { a = c32[2 * pair];      b = c32[2 * pair + 1]; }
    if (flip) { int t = a; a = b; b = t; }
}

// ---------------- K0: per-row squared norms, pre-scaled by log2(e) ----------------
__global__ __launch_bounds__(256)
void row_norms(const float* __restrict__ seq, float* __restrict__ norms, int nrows) {
    const int r = blockIdx.x * 256 + threadIdx.x;
    if (r >= nrows) return;
    const float* p = seq + (size_t)r * D;
    float s = 0.f;
    #pragma unroll
    for (int c = 0; c < 8; ++c) {
        float4 v = *(const float4*)(p + 4 * c);
        s = fmaf(v.x, v.x, fmaf(v.y, v.y, fmaf(v.z, v.z, fmaf(v.w, v.w, s))));
    }
    norms[r] = LOG2E * s;
}

// ---------------- K1: phase-A partial, exp2-domain, reg double-buffer ----------------
// e_j = exp2(L*(2 x.y - |y|^2 - |x|^2)) = exp(-d1) <= ~1 : branch-free, shared shift.
// ws1 slot (33 fields, field-major): f=0: s, f=1..32: acc[d]
__global__ __launch_bounds__(NT)
void ccl_phaseA(const float* __restrict__ seq, const int* __restrict__ src_len,
                const void* __restrict__ comb, const float* __restrict__ norms,
                float* __restrict__ ws1, int T, int B, int C, int JS, int JC) {
    const int dir = blockIdx.x, pair = dir >> 1, flip = dir & 1;
    int a, b; decode_pair(comb, B, C, pair, flip, a, b);
    const int Lx = src_len[a] >> 2, Ly = src_len[b] >> 2;
    const int r0 = blockIdx.y * NT;
    if (r0 >= Lx) return;
    const int js = blockIdx.z;
    const int j0 = js * JC;
    if (j0 >= Ly) return;
    const int j1 = min(Ly, j0 + JC);
    const int tid = threadIdx.x;
    const int i = r0 + tid;
    const int ic = min(i, Lx - 1);

    const float* __restrict__ xbase = seq + (size_t)a * T * D;
    const float* __restrict__ ybase = seq + (size_t)b * T * D;
    const float* __restrict__ ny = norms + (size_t)b * T;

    float x2[D];
    {
        const float* xr = xbase + (size_t)ic * D;
        const float k2 = 2.f * LOG2E;
        #pragma unroll
        for (int c = 0; c < 8; ++c) {
            float4 v = *(const float4*)(xr + 4 * c);
            x2[4*c]=k2*v.x; x2[4*c+1]=k2*v.y; x2[4*c+2]=k2*v.z; x2[4*c+3]=k2*v.w;
        }
    }
    const float shift0 = -norms[(size_t)a * T + ic];   // -L*|x_i|^2

    float s = 0.f;
    float acc[D];
    #pragma unroll
    for (int d = 0; d < D; ++d) acc[d] = 0.f;

    float Av[D], Bv[D], An, Bn;

#define LOADY(BUF, BN, idx) { const float* _r = ybase + (size_t)(idx) * D; \
    _Pragma("unroll") for (int c = 0; c < 8; ++c) *(float4*)&BUF[4*c] = *(const float4*)(_r + 4*c); \
    BN = ny[idx]; }

#define COMPA(BUF, BN) { \
    float d0 = shift0 - BN, d1 = 0.f, d2 = 0.f, d3 = 0.f; \
    _Pragma("unroll") for (int d = 0; d < D; d += 4) { \
        d0 = fmaf(x2[d+0], BUF[d+0], d0); d1 = fmaf(x2[d+1], BUF[d+1], d1); \
        d2 = fmaf(x2[d+2], BUF[d+2], d2); d3 = fmaf(x2[d+3], BUF[d+3], d3); } \
    const float e = exp2f((d0 + d1) + (d2 + d3)); \
    s += e; \
    _Pragma("unroll") for (int d = 0; d < D; ++d) acc[d] = fmaf(e, BUF[d], acc[d]); }

    int j = j0;
    LOADY(Av, An, j0);
    for (; j + 2 <= j1; j += 2) {
        LOADY(Bv, Bn, j + 1);
        COMPA(Av, An);
        LOADY(Av, An, min(j + 2, j1 - 1));
        COMPA(Bv, Bn);
    }
    if (j < j1) { COMPA(Av, An); }
#undef LOADY
#undef COMPA

    if (i < T) {
        float* slot = ws1 + (size_t)(dir * JS + js) * 33 * T;
        slot[i] = s;
        #pragma unroll
        for (int d = 0; d < D; ++d) slot[(size_t)(1 + d) * T + i] = acc[d];
    }
}

// ---------------- K1.5: merge -> ws3 row-major [dir][i][36]: 0..31 = 2L*snn, 32 = -L*|snn|^2 ----------------
__global__ __launch_bounds__(NT)
void ccl_merge_snn(const float* __restrict__ ws1, const int* __restrict__ src_len,
                   const void* __restrict__ comb, float* __restrict__ ws3,
                   int T, int B, int C, int JS, int JC) {
    const int dir = blockIdx.x, pair = dir >> 1, flip = dir & 1;
    int a, b; decode_pair(comb, B, C, pair, flip, a, b);
    const int Lx = src_len[a] >> 2, Ly = src_len[b] >> 2;
    const int r0 = blockIdx.y * NT;
    if (r0 >= Lx) return;
    const int i = r0 + threadIdx.x;
    if (i >= T) return;
    const int nch = min(JS, (Ly + JC - 1) / JC);

    float S = 0.f;
    float sn[D];
    #pragma unroll
    for (int d = 0; d < D; ++d) sn[d] = 0.f;
    for (int ch = 0; ch < nch; ++ch) {
        const float* slot = ws1 + (size_t)(dir * JS + ch) * 33 * T;
        S += slot[i];
        #pragma unroll
        for (int d = 0; d < D; ++d) sn[d] += slot[(size_t)(1 + d) * T + i];
    }
    const float inv = 1.f / S;
    float m2 = 0.f;
    #pragma unroll
    for (int d = 0; d < D; ++d) { sn[d] *= inv; m2 = fmaf(sn[d], sn[d], m2); }
    float* o = ws3 + ((size_t)dir * T + i) * 36;
    const float k2 = 2.f * LOG2E;
    #pragma unroll
    for (int d = 0; d < D; ++d) o[d] = k2 * sn[d];
    o[D] = -LOG2E * m2;
}

// ---------------- K2: phase-B partial, fp32 chunk-centered moments ----------------
// ws2 slot (3 float fields): f=0: s, f=1: s1, f=2: s2  (centered at chunk mid)
__global__ __launch_bounds__(NT)
void ccl_phaseB(const float* __restrict__ seq, const int* __restrict__ src_len,
                const void* __restrict__ comb, const float* __restrict__ norms,
                const float* __restrict__ ws3, float* __restrict__ ws2,
                int T, int B, int C, int KS, int KC) {
    const int dir = blockIdx.x, pair = dir >> 1, flip = dir & 1;
    int a, b; decode_pair(comb, B, C, pair, flip, a, b);
    const int Lx = src_len[a] >> 2;
    const int r0 = blockIdx.y * NT;
    if (r0 >= Lx) return;
    const int ks = blockIdx.z;
    const int k0 = ks * KC;
    if (k0 >= Lx) return;
    const int k1 = min(Lx, k0 + KC);
    const int tid = threadIdx.x;
    const int i = r0 + tid;
    const int ic = min(i, T - 1);
    const int kmid = k0 + (KC >> 1);

    const float* __restrict__ xbase = seq + (size_t)a * T * D;
    const float* __restrict__ nx = norms + (size_t)a * T;

    float sn2[D];
    float shift0;
    {
        const float* p = ws3 + ((size_t)dir * T + ic) * 36;
        #pragma unroll
        for (int c = 0; c < 8; ++c) *(float4*)&sn2[4*c] = *(const float4*)(p + 4*c);
        shift0 = p[D];                          // -L*|snn|^2
    }

    float s = 0.f, s1 = 0.f, s2 = 0.f;

    float Av[D], Bv[D], An, Bn;

#define LOADX(BUF, BN, idx) { const float* _r = xbase + (size_t)(idx) * D; \
    _Pragma("unroll") for (int c = 0; c < 8; ++c) *(float4*)&BUF[4*c] = *(const float4*)(_r + 4*c); \
    BN = nx[idx]; }

#define COMPB(BUF, BN, kk) { \
    float d0 = shift0 - BN, d1 = 0.f, d2 = 0.f, d3 = 0.f; \
    _Pragma("unroll") for (int d = 0; d < D; d += 4) { \
        d0 = fmaf(sn2[d+0], BUF[d+0], d0); d1 = fmaf(sn2[d+1], BUF[d+1], d1); \
        d2 = fmaf(sn2[d+2], BUF[d+2], d2); d3 = fmaf(sn2[d+3], BUF[d+3], d3); } \
    const float e = exp2f((d0 + d1) + (d2 + d3)); \
    const float kc = (float)((kk) - kmid); \
    s += e; \
    s1 = fmaf(e, kc, s1); \
    s2 = fmaf(e * kc, kc, s2); }

    int k = k0;
    LOADX(Av, An, k0);
    for (; k + 2 <= k1; k += 2) {
        LOADX(Bv, Bn, k + 1);
        COMPB(Av, An, k);
        LOADX(Av, An, min(k + 2, k1 - 1));
        COMPB(Bv, Bn, k + 1);
    }
    if (k < k1) { COMPB(Av, An, k); }
#undef LOADX
#undef COMPB

    if (i < T) {
        float* slot = ws2 + (size_t)(dir * KS + ks) * 3 * T;
        slot[i] = s;
        slot[(size_t)T + i] = s1;
        slot[(size_t)2 * T + i] = s2;
    }
}

// ---------------- K3: merge phase-B partials (fp64 shift-to-i) -> li -> sum ----------------
__global__ __launch_bounds__(NT)
void ccl_final(const float* __restrict__ ws2, const int* __restrict__ src_len,
               const void* __restrict__ comb, float* __restrict__ out,
               int T, int B, int C, int KS, int KC) {
    const int dir = blockIdx.x, pair = dir >> 1, flip = dir & 1;
    int a, b; decode_pair(comb, B, C, pair, flip, a, b);
    const int Lx = src_len[a] >> 2;
    const int r0 = blockIdx.y * NT;
    if (r0 >= Lx) return;
    const int tid = threadIdx.x;
    const int i = r0 + tid;
    const int nch = min(KS, (Lx + KC - 1) / KC);

    float li = 0.f;
    if (i < Lx) {
        double S = 0.0, S1 = 0.0, S2 = 0.0;      // centered at i
        for (int ch = 0; ch < nch; ++ch) {
            const float* slot = ws2 + (size_t)(dir * KS + ch) * 3 * T;
            const double sc  = (double)slot[i];
            const double s1c = (double)slot[(size_t)T + i];
            const double s2c = (double)slot[(size_t)2 * T + i];
            const double dc = (double)(ch * KC + (KC >> 1) - i);   // kmid_c - i
            S  += sc;
            S1 += s1c + dc * sc;
            S2 += s2c + dc * (2.0 * s1c + dc * sc);
        }
        const double inv = 1.0 / S;
        const double du = S1 * inv;                    // u - i
        const double var = fma(-du, du, S2 * inv);
        li = (float)(du * du / var) + 0.005f * __logf((float)var);
    }

    float wsum = li;
    #pragma unroll
    for (int off = 32; off > 0; off >>= 1) wsum += __shfl_down(wsum, off, 64);
    __shared__ float red[NT / 64];
    if ((tid & 63) == 0) red[tid >> 6] = wsum;
    __syncthreads();
    if (tid == 0) {
        float t = 0.f;
        #pragma unroll
        for (int w = 0; w < NT / 64; ++w) t += red[w];
        atomicAdd(out, t / (float)C);
    }
}

// ---------------- Fallback: monolithic (known correct) ----------------
__global__ void ccl_mono(const float* __restrict__ seq, const int* __restrict__ src_len,
                         const void* __restrict__ comb, float* __restrict__ out,
                         int T, int B, int C) {
    const int dir = blockIdx.x, pair = dir >> 1, flip = dir & 1;
    int a, b; decode_pair(comb, B, C, pair, flip, a, b);
    const int Lx = src_len[a] >> 2, Ly = src_len[b] >> 2;
    if (blockIdx.y * 64 >= Lx) return;
    const int tid = threadIdx.x;
    const int i = blockIdx.y * 64 + tid;
    const bool valid = (i < Lx);
    const float* __restrict__ xbase = seq + (size_t)a * T * D;
    const float* __restrict__ ybase = seq + (size_t)b * T * D;
    float x[D];
    {
        const float* xr = xbase + (size_t)(valid ? i : (Lx - 1)) * D;
        #pragma unroll
        for (int c = 0; c < 8; ++c) {
            float4 v = *(const float4*)(xr + 4 * c);
            x[4*c] = 2.f*v.x; x[4*c+1] = 2.f*v.y; x[4*c+2] = 2.f*v.z; x[4*c+3] = 2.f*v.w;
        }
    }
    float m = -3.4e38f, s = 0.f;
    float acc[D];
    #pragma unroll
    for (int d = 0; d < D; ++d) acc[d] = 0.f;
    for (int j = 0; j < Ly; ++j) {
        const float* yr = ybase + (size_t)j * D;
        float yv[D]; float q2 = 0.f;
        #pragma unroll
        for (int d = 0; d < D; ++d) { yv[d] = yr[d]; q2 = fmaf(yv[d], yv[d], q2); }
        float d0 = -q2, d1 = 0.f, d2 = 0.f, d3 = 0.f;
        #pragma unroll
        for (int d = 0; d < D; d += 4) {
            d0 = fmaf(x[d], yv[d], d0); d1 = fmaf(x[d+1], yv[d+1], d1);
            d2 = fmaf(x[d+2], yv[d+2], d2); d3 = fmaf(x[d+3], yv[d+3], d3);
        }
        const float sc = (d0 + d1) + (d2 + d3);
        if (__any(sc > m + 8.f)) {
            const float mn = fmaxf(m, sc);
            const float scale = __expf(m - mn);
            const float e = __expf(sc - mn);
            s = fmaf(s, scale, e);
            #pragma unroll
            for (int d = 0; d < D; ++d) acc[d] = fmaf(acc[d], scale, e * yv[d]);
            m = mn;
        } else {
            const float e = __expf(sc - m);
            s += e;
            #pragma unroll
            for (int d = 0; d < D; ++d) acc[d] = fmaf(e, yv[d], acc[d]);
        }
    }
    { const float inv_s = 2.f / s;
      #pragma unroll
      for (int d = 0; d < D; ++d) acc[d] *= inv_s; }
    float mb = -3.4e38f;
    double sb = 0.0, s1 = 0.0, s2m = 0.0;
    const float fi = (float)i;
    for (int k = 0; k < Lx; ++k) {
        const float* xr = xbase + (size_t)k * D;
        float xv[D]; float q2 = 0.f;
        #pragma unroll
        for (int d = 0; d < D; ++d) { xv[d] = xr[d]; q2 = fmaf(xv[d], xv[d], q2); }
        float d0 = -q2, d1 = 0.f, d2 = 0.f, d3 = 0.f;
        #pragma unroll
        for (int d = 0; d < D; d += 4) {
            d0 = fmaf(acc[d], xv[d], d0); d1 = fmaf(acc[d+1], xv[d+1], d1);
            d2 = fmaf(acc[d+2], xv[d+2], d2); d3 = fmaf(acc[d+3], xv[d+3], d3);
        }
        const float sc = (d0 + d1) + (d2 + d3);
        const float kc = (float)k - fi;
        if (__any(sc > mb + 8.f)) {
            const float mn = fmaxf(mb, sc);
            const double scale = (double)__expf(mb - mn);
            const double e = (double)__expf(sc - mn);
            sb = sb * scale + e; s1 = s1 * scale + e * kc; s2m = s2m * scale + e * kc * kc;
            mb = mn;
        } else {
            const double e = (double)__expf(sc - mb);
            sb += e; s1 = fma(e, (double)kc, s1); s2m = fma(e * kc, (double)kc, s2m);
        }
    }
    float li = 0.f;
    if (valid) {
        const double inv = 1.0 / sb;
        const double du = s1 * inv;
        const double var = fma(-du, du, s2m * inv);
        li = (float)(du * du / var) + 0.005f * __logf((float)var);
    }
    float wsum = li;
    #pragma unroll
    for (int off = 32; off > 0; off >>= 1) wsum += __shfl_down(wsum, off, 64);
    if (tid == 0) atomicAdd(out, wsum * (1.0f / (float)C));
}

extern "C" void kernel_launch(void* const* d_in, const int* in_sizes, int n_in,
                              void* d_out, int out_size, void* d_ws, size_t ws_size,
                              hipStream_t stream) {
    const float* seq = (const float*)d_in[0];
    const int* src_len = (const int*)d_in[1];
    const void* comb = (const void*)d_in[2];
    float* out = (float*)d_out;

    const int B = in_sizes[1];
    const int C = in_sizes[2] / 2;
    const int T = in_sizes[0] / (B * D);
    const int RT = (T + NT - 1) / NT;
    const int nrows = B * T;

    auto need = [&](int js, int ks) -> size_t {
        return 4 * ((size_t)nrows
                    + (size_t)2 * C * js * 33 * T     // ws1
                    + (size_t)2 * C * T * 36          // ws3
                    + (size_t)2 * C * ks * 3 * T);    // ws2
    };
    int JS = 16, KS = 32;
    while (JS > 1 && need(JS, KS) > ws_size) { JS >>= 1; KS >>= 1; }

    hipMemsetAsync(out, 0, sizeof(float), stream);

    if (need(JS, KS) <= ws_size) {
        const int JC = (T + JS - 1) / JS;
        const int KC = (T + KS - 1) / KS;
        float* norms = (float*)d_ws;
        float* ws1 = norms + nrows;
        float* ws3 = ws1 + (size_t)2 * C * JS * 33 * T;
        float* ws2 = ws3 + (size_t)2 * C * T * 36;
        row_norms<<<(nrows + 255) / 256, 256, 0, stream>>>(seq, norms, nrows);
        ccl_phaseA<<<dim3(2 * C, RT, JS), NT, 0, stream>>>(seq, src_len, comb, norms, ws1, T, B, C, JS, JC);
        ccl_merge_snn<<<dim3(2 * C, RT), NT, 0, stream>>>(ws1, src_len, comb, ws3, T, B, C, JS, JC);
        ccl_phaseB<<<dim3(2 * C, RT, KS), NT, 0, stream>>>(seq, src_len, comb, norms, ws3, ws2, T, B, C, KS, KC);
        ccl_final<<<dim3(2 * C, RT), NT, 0, stream>>>(ws2, src_len, comb, out, T, B, C, KS, KC);
    } else {
        dim3 grid(2 * C, (T + 63) / 64);
        ccl_mono<<<grid, 64, 0, stream>>>(seq, src_len, comb, out, T, B, C);
    }
}

// Round 8
// 548.048 us; speedup vs baseline: 1.0929x; 1.0929x over previous
//
#include <hip/hip_runtime.h>

#define D 32
#define NT 128
#define LOG2E 1.4426950408889634f

__device__ __forceinline__ void decode_pair(const void* comb, int B, int C,
                                            int pair, int flip, int& a, int& b) {
    const long long* c64 = (const long long*)comb;
    const int* c32 = (const int*)comb;
    bool is64 = true;
    for (int q = 0; q < C; ++q) {
        long long v = c64[q];
        if (v < 0 || v >= (long long)B) { is64 = false; break; }
    }
    if (is64) { a = (int)c64[2 * pair]; b = (int)c64[2 * pair + 1]; }
    else      { a = c32[2 * pair];      b = c32[2 * pair + 1]; }
    if (flip) { int t = a; a = b; b = t; }
}

// ---------------- K0: per-row squared norms, pre-scaled by log2(e) ----------------
__global__ __launch_bounds__(256)
void row_norms(const float* __restrict__ seq, float* __restrict__ norms, int nrows) {
    const int r = blockIdx.x * 256 + threadIdx.x;
    if (r >= nrows) return;
    const float* p = seq + (size_t)r * D;
    float s = 0.f;
    #pragma unroll
    for (int c = 0; c < 8; ++c) {
        float4 v = *(const float4*)(p + 4 * c);
        s = fmaf(v.x, v.x, fmaf(v.y, v.y, fmaf(v.z, v.z, fmaf(v.w, v.w, s))));
    }
    norms[r] = LOG2E * s;
}

// ---------------- K1: phase-A partial, R=2 rows/lane, exp2-domain, branch-free ----------------
// ws1 slot (33 fields, field-major): f=0: s, f=1..32: acc[d]
__global__ __launch_bounds__(NT)
void ccl_phaseA(const float* __restrict__ seq, const int* __restrict__ src_len,
                const void* __restrict__ comb, const float* __restrict__ norms,
                float* __restrict__ ws1, int T, int B, int C, int JS, int JC) {
    const int dir = blockIdx.x, pair = dir >> 1, flip = dir & 1;
    int a, b; decode_pair(comb, B, C, pair, flip, a, b);
    const int Lx = src_len[a] >> 2, Ly = src_len[b] >> 2;
    const int r0 = blockIdx.y * (2 * NT);
    if (r0 >= Lx) return;
    const int js = blockIdx.z;
    const int j0 = js * JC;
    if (j0 >= Ly) return;
    const int j1 = min(Ly, j0 + JC);
    const int tid = threadIdx.x;
    const int iA = r0 + tid;
    const int iB = iA + NT;
    const int icA = min(iA, Lx - 1);
    const int icB = min(iB, Lx - 1);

    const float* __restrict__ xbase = seq + (size_t)a * T * D;
    const float* __restrict__ ybase = seq + (size_t)b * T * D;
    const float* __restrict__ ny = norms + (size_t)b * T;

    float xA[D], xB[D];
    {
        const float k2 = 2.f * LOG2E;
        const float* ra = xbase + (size_t)icA * D;
        const float* rb = xbase + (size_t)icB * D;
        #pragma unroll
        for (int c = 0; c < 8; ++c) {
            float4 va = *(const float4*)(ra + 4 * c);
            float4 vb = *(const float4*)(rb + 4 * c);
            xA[4*c]=k2*va.x; xA[4*c+1]=k2*va.y; xA[4*c+2]=k2*va.z; xA[4*c+3]=k2*va.w;
            xB[4*c]=k2*vb.x; xB[4*c+1]=k2*vb.y; xB[4*c+2]=k2*vb.z; xB[4*c+3]=k2*vb.w;
        }
    }
    const float shA = -norms[(size_t)a * T + icA];
    const float shB = -norms[(size_t)a * T + icB];

    float sA = 0.f, sB = 0.f;
    float accA[D], accB[D];
    #pragma unroll
    for (int d = 0; d < D; ++d) { accA[d] = 0.f; accB[d] = 0.f; }

    #pragma unroll 2
    for (int j = j0; j < j1; ++j) {
        const float* yr = ybase + (size_t)j * D;     // wave-uniform address
        float yv[D];
        #pragma unroll
        for (int c = 0; c < 8; ++c) *(float4*)&yv[4*c] = *(const float4*)(yr + 4*c);
        const float nyj = ny[j];
        float a0 = shA - nyj, a1 = 0.f, a2 = 0.f, a3 = 0.f;
        float b0 = shB - nyj, b1 = 0.f, b2 = 0.f, b3 = 0.f;
        #pragma unroll
        for (int d = 0; d < D; d += 4) {
            a0 = fmaf(xA[d+0], yv[d+0], a0); a1 = fmaf(xA[d+1], yv[d+1], a1);
            a2 = fmaf(xA[d+2], yv[d+2], a2); a3 = fmaf(xA[d+3], yv[d+3], a3);
            b0 = fmaf(xB[d+0], yv[d+0], b0); b1 = fmaf(xB[d+1], yv[d+1], b1);
            b2 = fmaf(xB[d+2], yv[d+2], b2); b3 = fmaf(xB[d+3], yv[d+3], b3);
        }
        const float eA = exp2f((a0 + a1) + (a2 + a3));
        const float eB = exp2f((b0 + b1) + (b2 + b3));
        sA += eA; sB += eB;
        #pragma unroll
        for (int d = 0; d < D; ++d) {
            accA[d] = fmaf(eA, yv[d], accA[d]);
            accB[d] = fmaf(eB, yv[d], accB[d]);
        }
    }

    float* slot = ws1 + (size_t)(dir * JS + js) * 33 * T;
    if (iA < T) {
        slot[iA] = sA;
        #pragma unroll
        for (int d = 0; d < D; ++d) slot[(size_t)(1 + d) * T + iA] = accA[d];
    }
    if (iB < T) {
        slot[iB] = sB;
        #pragma unroll
        for (int d = 0; d < D; ++d) slot[(size_t)(1 + d) * T + iB] = accB[d];
    }
}

// ---------------- K1.5: merge -> ws3 row-major [dir][i][36]: 0..31 = 2L*snn, 32 = -L*|snn|^2 ----------------
__global__ __launch_bounds__(NT)
void ccl_merge_snn(const float* __restrict__ ws1, const int* __restrict__ src_len,
                   const void* __restrict__ comb, float* __restrict__ ws3,
                   int T, int B, int C, int JS, int JC) {
    const int dir = blockIdx.x, pair = dir >> 1, flip = dir & 1;
    int a, b; decode_pair(comb, B, C, pair, flip, a, b);
    const int Lx = src_len[a] >> 2, Ly = src_len[b] >> 2;
    const int r0 = blockIdx.y * NT;
    if (r0 >= Lx) return;
    const int i = r0 + threadIdx.x;
    if (i >= T) return;
    const int nch = min(JS, (Ly + JC - 1) / JC);

    float S = 0.f;
    float sn[D];
    #pragma unroll
    for (int d = 0; d < D; ++d) sn[d] = 0.f;
    for (int ch = 0; ch < nch; ++ch) {
        const float* slot = ws1 + (size_t)(dir * JS + ch) * 33 * T;
        S += slot[i];
        #pragma unroll
        for (int d = 0; d < D; ++d) sn[d] += slot[(size_t)(1 + d) * T + i];
    }
    const float inv = 1.f / S;
    float m2 = 0.f;
    #pragma unroll
    for (int d = 0; d < D; ++d) { sn[d] *= inv; m2 = fmaf(sn[d], sn[d], m2); }
    float* o = ws3 + ((size_t)dir * T + i) * 36;
    const float k2 = 2.f * LOG2E;
    #pragma unroll
    for (int d = 0; d < D; ++d) o[d] = k2 * sn[d];
    o[D] = -LOG2E * m2;
}

// ---------------- K2: phase-B partial, R=2 rows/lane, fp32 chunk-centered moments ----------------
// ws2 slot (3 float fields): f=0: s, f=1: s1, f=2: s2  (centered at chunk mid)
__global__ __launch_bounds__(NT)
void ccl_phaseB(const float* __restrict__ seq, const int* __restrict__ src_len,
                const void* __restrict__ comb, const float* __restrict__ norms,
                const float* __restrict__ ws3, float* __restrict__ ws2,
                int T, int B, int C, int KS, int KC) {
    const int dir = blockIdx.x, pair = dir >> 1, flip = dir & 1;
    int a, b; decode_pair(comb, B, C, pair, flip, a, b);
    const int Lx = src_len[a] >> 2;
    const int r0 = blockIdx.y * (2 * NT);
    if (r0 >= Lx) return;
    const int ks = blockIdx.z;
    const int k0 = ks * KC;
    if (k0 >= Lx) return;
    const int k1 = min(Lx, k0 + KC);
    const int tid = threadIdx.x;
    const int iA = r0 + tid;
    const int iB = iA + NT;
    const int icA = min(iA, T - 1);
    const int icB = min(iB, T - 1);
    const int kmid = k0 + (KC >> 1);

    const float* __restrict__ xbase = seq + (size_t)a * T * D;
    const float* __restrict__ nx = norms + (size_t)a * T;

    float snA[D], snB[D];
    float shAv, shBv;
    {
        const float* pa = ws3 + ((size_t)dir * T + icA) * 36;
        const float* pb = ws3 + ((size_t)dir * T + icB) * 36;
        #pragma unroll
        for (int c = 0; c < 8; ++c) {
            *(float4*)&snA[4*c] = *(const float4*)(pa + 4*c);
            *(float4*)&snB[4*c] = *(const float4*)(pb + 4*c);
        }
        shAv = pa[D];
        shBv = pb[D];
    }

    float sAq = 0.f, s1A = 0.f, s2A = 0.f;
    float sBq = 0.f, s1B = 0.f, s2B = 0.f;
    const float cA = (float)(iA - kmid);   // (k - iA) = (k - kmid) + kmid - iA ... we accumulate centered at kmid
    const float cB = (float)(iB - kmid);
    (void)cA; (void)cB;

    #pragma unroll 2
    for (int k = k0; k < k1; ++k) {
        const float* xr = xbase + (size_t)k * D;     // wave-uniform address
        float xv[D];
        #pragma unroll
        for (int c = 0; c < 8; ++c) *(float4*)&xv[4*c] = *(const float4*)(xr + 4*c);
        const float nk = nx[k];
        float a0 = shAv - nk, a1 = 0.f, a2 = 0.f, a3 = 0.f;
        float b0 = shBv - nk, b1 = 0.f, b2 = 0.f, b3 = 0.f;
        #pragma unroll
        for (int d = 0; d < D; d += 4) {
            a0 = fmaf(snA[d+0], xv[d+0], a0); a1 = fmaf(snA[d+1], xv[d+1], a1);
            a2 = fmaf(snA[d+2], xv[d+2], a2); a3 = fmaf(snA[d+3], xv[d+3], a3);
            b0 = fmaf(snB[d+0], xv[d+0], b0); b1 = fmaf(snB[d+1], xv[d+1], b1);
            b2 = fmaf(snB[d+2], xv[d+2], b2); b3 = fmaf(snB[d+3], xv[d+3], b3);
        }
        const float eA = exp2f((a0 + a1) + (a2 + a3));
        const float eB = exp2f((b0 + b1) + (b2 + b3));
        const float kc = (float)(k - kmid);
        sAq += eA; sBq += eB;
        s1A = fmaf(eA, kc, s1A); s1B = fmaf(eB, kc, s1B);
        s2A = fmaf(eA * kc, kc, s2A); s2B = fmaf(eB * kc, kc, s2B);
    }

    float* slot = ws2 + (size_t)(dir * KS + ks) * 3 * T;
    if (iA < T) {
        slot[iA] = sAq;
        slot[(size_t)T + iA] = s1A;
        slot[(size_t)2 * T + iA] = s2A;
    }
    if (iB < T) {
        slot[iB] = sBq;
        slot[(size_t)T + iB] = s1B;
        slot[(size_t)2 * T + iB] = s2B;
    }
}

// ---------------- K3: merge phase-B partials (fp64 shift-to-i) -> li -> sum ----------------
__global__ __launch_bounds__(NT)
void ccl_final(const float* __restrict__ ws2, const int* __restrict__ src_len,
               const void* __restrict__ comb, float* __restrict__ out,
               int T, int B, int C, int KS, int KC) {
    const int dir = blockIdx.x, pair = dir >> 1, flip = dir & 1;
    int a, b; decode_pair(comb, B, C, pair, flip, a, b);
    const int Lx = src_len[a] >> 2;
    const int r0 = blockIdx.y * NT;
    if (r0 >= Lx) return;
    const int tid = threadIdx.x;
    const int i = r0 + tid;
    const int nch = min(KS, (Lx + KC - 1) / KC);

    float li = 0.f;
    if (i < Lx) {
        double S = 0.0, S1 = 0.0, S2 = 0.0;      // centered at i
        for (int ch = 0; ch < nch; ++ch) {
            const float* slot = ws2 + (size_t)(dir * KS + ch) * 3 * T;
            const double sc  = (double)slot[i];
            const double s1c = (double)slot[(size_t)T + i];
            const double s2c = (double)slot[(size_t)2 * T + i];
            const double dc = (double)(ch * KC + (KC >> 1) - i);   // kmid_c - i
            S  += sc;
            S1 += s1c + dc * sc;
            S2 += s2c + dc * (2.0 * s1c + dc * sc);
        }
        const double inv = 1.0 / S;
        const double du = S1 * inv;                    // u - i
        const double var = fma(-du, du, S2 * inv);
        li = (float)(du * du / var) + 0.005f * __logf((float)var);
    }

    float wsum = li;
    #pragma unroll
    for (int off = 32; off > 0; off >>= 1) wsum += __shfl_down(wsum, off, 64);
    __shared__ float red[NT / 64];
    if ((tid & 63) == 0) red[tid >> 6] = wsum;
    __syncthreads();
    if (tid == 0) {
        float t = 0.f;
        #pragma unroll
        for (int w = 0; w < NT / 64; ++w) t += red[w];
        atomicAdd(out, t / (float)C);
    }
}

// ---------------- Fallback: monolithic (known correct) ----------------
__global__ void ccl_mono(const float* __restrict__ seq, const int* __restrict__ src_len,
                         const void* __restrict__ comb, float* __restrict__ out,
                         int T, int B, int C) {
    const int dir = blockIdx.x, pair = dir >> 1, flip = dir & 1;
    int a, b; decode_pair(comb, B, C, pair, flip, a, b);
    const int Lx = src_len[a] >> 2, Ly = src_len[b] >> 2;
    if (blockIdx.y * 64 >= Lx) return;
    const int tid = threadIdx.x;
    const int i = blockIdx.y * 64 + tid;
    const bool valid = (i < Lx);
    const float* __restrict__ xbase = seq + (size_t)a * T * D;
    const float* __restrict__ ybase = seq + (size_t)b * T * D;
    float x[D];
    {
        const float* xr = xbase + (size_t)(valid ? i : (Lx - 1)) * D;
        #pragma unroll
        for (int c = 0; c < 8; ++c) {
            float4 v = *(const float4*)(xr + 4 * c);
            x[4*c] = 2.f*v.x; x[4*c+1] = 2.f*v.y; x[4*c+2] = 2.f*v.z; x[4*c+3] = 2.f*v.w;
        }
    }
    float m = -3.4e38f, s = 0.f;
    float acc[D];
    #pragma unroll
    for (int d = 0; d < D; ++d) acc[d] = 0.f;
    for (int j = 0; j < Ly; ++j) {
        const float* yr = ybase + (size_t)j * D;
        float yv[D]; float q2 = 0.f;
        #pragma unroll
        for (int d = 0; d < D; ++d) { yv[d] = yr[d]; q2 = fmaf(yv[d], yv[d], q2); }
        float d0 = -q2, d1 = 0.f, d2 = 0.f, d3 = 0.f;
        #pragma unroll
        for (int d = 0; d < D; d += 4) {
            d0 = fmaf(x[d], yv[d], d0); d1 = fmaf(x[d+1], yv[d+1], d1);
            d2 = fmaf(x[d+2], yv[d+2], d2); d3 = fmaf(x[d+3], yv[d+3], d3);
        }
        const float sc = (d0 + d1) + (d2 + d3);
        if (__any(sc > m + 8.f)) {
            const float mn = fmaxf(m, sc);
            const float scale = __expf(m - mn);
            const float e = __expf(sc - mn);
            s = fmaf(s, scale, e);
            #pragma unroll
            for (int d = 0; d < D; ++d) acc[d] = fmaf(acc[d], scale, e * yv[d]);
            m = mn;
        } else {
            const float e = __expf(sc - m);
            s += e;
            #pragma unroll
            for (int d = 0; d < D; ++d) acc[d] = fmaf(e, yv[d], acc[d]);
        }
    }
    { const float inv_s = 2.f / s;
      #pragma unroll
      for (int d = 0; d < D; ++d) acc[d] *= inv_s; }
    float mb = -3.4e38f;
    double sb = 0.0, s1 = 0.0, s2m = 0.0;
    const float fi = (float)i;
    for (int k = 0; k < Lx; ++k) {
        const float* xr = xbase + (size_t)k * D;
        float xv[D]; float q2 = 0.f;
        #pragma unroll
        for (int d = 0; d < D; ++d) { xv[d] = xr[d]; q2 = fmaf(xv[d], xv[d], q2); }
        float d0 = -q2, d1 = 0.f, d2 = 0.f, d3 = 0.f;
        #pragma unroll
        for (int d = 0; d < D; d += 4) {
            d0 = fmaf(acc[d], xv[d], d0); d1 = fmaf(acc[d+1], xv[d+1], d1);
            d2 = fmaf(acc[d+2], xv[d+2], d2); d3 = fmaf(acc[d+3], xv[d+3], d3);
        }
        const float sc = (d0 + d1) + (d2 + d3);
        const float kc = (float)k - fi;
        if (__any(sc > mb + 8.f)) {
            const float mn = fmaxf(mb, sc);
            const double scale = (double)__expf(mb - mn);
            const double e = (double)__expf(sc - mn);
            sb = sb * scale + e; s1 = s1 * scale + e * kc; s2m = s2m * scale + e * kc * kc;
            mb = mn;
        } else {
            const double e = (double)__expf(sc - mb);
            sb += e; s1 = fma(e, (double)kc, s1); s2m = fma(e * kc, (double)kc, s2m);
        }
    }
    float li = 0.f;
    if (valid) {
        const double inv = 1.0 / sb;
        const double du = s1 * inv;
        const double var = fma(-du, du, s2m * inv);
        li = (float)(du * du / var) + 0.005f * __logf((float)var);
    }
    float wsum = li;
    #pragma unroll
    for (int off = 32; off > 0; off >>= 1) wsum += __shfl_down(wsum, off, 64);
    if (tid == 0) atomicAdd(out, wsum * (1.0f / (float)C));
}

extern "C" void kernel_launch(void* const* d_in, const int* in_sizes, int n_in,
                              void* d_out, int out_size, void* d_ws, size_t ws_size,
                              hipStream_t stream) {
    const float* seq = (const float*)d_in[0];
    const int* src_len = (const int*)d_in[1];
    const void* comb = (const void*)d_in[2];
    float* out = (float*)d_out;

    const int B = in_sizes[1];
    const int C = in_sizes[2] / 2;
    const int T = in_sizes[0] / (B * D);
    const int RT = (T + NT - 1) / NT;              // merge/final row blocks
    const int RT2 = (T + 2 * NT - 1) / (2 * NT);   // phase kernels (R=2 rows/lane)
    const int nrows = B * T;

    auto need = [&](int js, int ks) -> size_t {
        return 4 * ((size_t)nrows
                    + (size_t)2 * C * js * 33 * T     // ws1
                    + (size_t)2 * C * T * 36          // ws3
                    + (size_t)2 * C * ks * 3 * T);    // ws2
    };
    int JS = 16, KS = 32;
    while (JS > 1 && need(JS, KS) > ws_size) { JS >>= 1; KS >>= 1; }

    hipMemsetAsync(out, 0, sizeof(float), stream);

    if (need(JS, KS) <= ws_size) {
        const int JC = (T + JS - 1) / JS;
        const int KC = (T + KS - 1) / KS;
        float* norms = (float*)d_ws;
        float* ws1 = norms + nrows;
        float* ws3 = ws1 + (size_t)2 * C * JS * 33 * T;
        float* ws2 = ws3 + (size_t)2 * C * T * 36;
        row_norms<<<(nrows + 255) / 256, 256, 0, stream>>>(seq, norms, nrows);
        ccl_phaseA<<<dim3(2 * C, RT2, JS), NT, 0, stream>>>(seq, src_len, comb, norms, ws1, T, B, C, JS, JC);
        ccl_merge_snn<<<dim3(2 * C, RT), NT, 0, stream>>>(ws1, src_len, comb, ws3, T, B, C, JS, JC);
        ccl_phaseB<<<dim3(2 * C, RT2, KS), NT, 0, stream>>>(seq, src_len, comb, norms, ws3, ws2, T, B, C, KS, KC);
        ccl_final<<<dim3(2 * C, RT), NT, 0, stream>>>(ws2, src_len, comb, out, T, B, C, KS, KC);
    } else {
        dim3 grid(2 * C, (T + 63) / 64);
        ccl_mono<<<grid, 64, 0, stream>>>(seq, src_len, comb, out, T, B, C);
    }
}